// Round 6
// baseline (308.270 us; speedup 1.0000x reference)
//
#include <hip/hip_runtime.h>

static constexpr int BLOCK = 256;   // 4 fully independent waves per block
static constexpr int TPS   = 256;   // samples per wave-tile
static constexpr int F4PW  = 192;   // float4 per array per wave-tile (256*12B/16B)
static constexpr int GRID0 = 2048;  // 8192 wave-streams; 32768 tiles -> 4 tiles/stream

typedef float f32x4 __attribute__((ext_vector_type(4)));
typedef int   i32x4 __attribute__((ext_vector_type(4)));

__device__ __forceinline__ float sample_contrib(float l0, float l1, float l2,
                                                float t0, float t1, float t2,
                                                float c, int lab) {
    float temp;
    if (c > 0.9f)      temp = 1.5f;
    else if (c > 0.6f) temp = 2.0f;
    else               temp = fminf(2.5f + (0.6f - c) * 2.0f, 3.0f);
    float invT = 1.0f / temp;

    float a0 = l0 * invT, a1 = l1 * invT, a2 = l2 * invT;
    float m  = fmaxf(a0, fmaxf(a1, a2));
    float s  = __expf(a0 - m) + __expf(a1 - m) + __expf(a2 - m);
    float lse = __logf(s) + m;

    float tlogt = t0 * __logf(t0) + t1 * __logf(t1) + t2 * __logf(t2);
    float ta    = t0 * a0 + t1 * a1 + t2 * a2;
    float kl    = tlogt - ta + lse;

    float m2 = fmaxf(l0, fmaxf(l1, l2));
    float s2 = __expf(l0 - m2) + __expf(l1 - m2) + __expf(l2 - m2);
    float lse2 = __logf(s2) + m2;
    float ll = (lab == 0) ? l0 : ((lab == 1) ? l1 : l2);
    float ce = lse2 - ll;

    return 0.5f * kl + 0.5f * ce;
}

// Barrier-free wave-private pipelines + NT (aux=2) on everything.
// Each of the 4 waves owns a private double-buffered LDS slice and its own
// tile stream; correctness needs only wave-local ordering via counted
// s_waitcnt vmcnt(8). ZERO barriers in the kernel, so per-CU the 12 resident
// waves stall independently (staggered) instead of in 3 lockstep convoys.
// Lane computes 4 CONSECUTIVE samples: LDS reads are 3x ds_read_b128 at
// word-stride 12 (8 lanes tile all 32 banks -> 2/bank = free), and conf/hard
// collapse to one NT float4 + one NT int4 load per tile.
__global__ __launch_bounds__(BLOCK) void adl_main(
    const float4* __restrict__ l4,
    const int*    __restrict__ hard,
    const float4* __restrict__ s4,
    const float*  __restrict__ conf,
    double*       __restrict__ ws_sum,
    int nt, long long B)
{
    // [wave][buf][arr(L=0,S=1)][768 floats]  = 49152 B -> 3 blocks/CU
    __shared__ __align__(16) float lds[4][2][2][TPS * 3];

    const int lane = threadIdx.x & 63;
    const int wid  = threadIdx.x >> 6;
    float part = 0.0f;

    // 8 vmem ops per STAGE: 3+3 global_load_lds (NT) + 1 conf4 + 1 hard4 (NT).
#define STAGE(BUF, TILE, CF, LB)                                                   \
    do {                                                                           \
        const float4* gl_ = l4 + (size_t)(TILE) * F4PW;                            \
        const float4* gs_ = s4 + (size_t)(TILE) * F4PW;                            \
        _Pragma("unroll")                                                          \
        for (int k = 0; k < 3; ++k)                                                \
            __builtin_amdgcn_global_load_lds(                                      \
                (const __attribute__((address_space(1))) void*)(gl_ + k * 64 + lane), \
                (__attribute__((address_space(3))) void*)(&lds[wid][BUF][0][(k * 64 + lane) * 4]), \
                16, 0, 2 /* NT */);                                                \
        _Pragma("unroll")                                                          \
        for (int k = 0; k < 3; ++k)                                                \
            __builtin_amdgcn_global_load_lds(                                      \
                (const __attribute__((address_space(1))) void*)(gs_ + k * 64 + lane), \
                (__attribute__((address_space(3))) void*)(&lds[wid][BUF][1][(k * 64 + lane) * 4]), \
                16, 0, 2 /* NT */);                                                \
        CF = __builtin_nontemporal_load((const f32x4*)conf + (size_t)(TILE) * 64 + lane); \
        LB = __builtin_nontemporal_load((const i32x4*)hard + (size_t)(TILE) * 64 + lane); \
    } while (0)

    // Wait until only the newest stage (8 ops) remains outstanding -> previous
    // tile's LDS writes + reg loads complete. Wave-local; no barrier anywhere.
#define WAIT8() asm volatile("s_waitcnt vmcnt(8)" ::: "memory")
#define WAIT0() asm volatile("s_waitcnt vmcnt(0)" ::: "memory")

#define COMPUTE(BUF, CF, LB)                                                       \
    do {                                                                           \
        const float* Lp = &lds[wid][BUF][0][12 * lane];                            \
        const float* Sp = &lds[wid][BUF][1][12 * lane];                            \
        f32x4 L0 = *(const f32x4*)(Lp);                                            \
        f32x4 L1 = *(const f32x4*)(Lp + 4);                                        \
        f32x4 L2 = *(const f32x4*)(Lp + 8);                                        \
        f32x4 S0 = *(const f32x4*)(Sp);                                            \
        f32x4 S1 = *(const f32x4*)(Sp + 4);                                        \
        f32x4 S2 = *(const f32x4*)(Sp + 8);                                        \
        part += sample_contrib(L0[0], L0[1], L0[2], S0[0], S0[1], S0[2], CF[0], LB[0]); \
        part += sample_contrib(L0[3], L1[0], L1[1], S0[3], S1[0], S1[1], CF[1], LB[1]); \
        part += sample_contrib(L1[2], L1[3], L2[0], S1[2], S1[3], S2[0], CF[2], LB[2]); \
        part += sample_contrib(L2[1], L2[2], L2[3], S2[1], S2[2], S2[3], CF[3], LB[3]); \
    } while (0)

    // wave-stream W handles tiles W, W+SW, W+2*SW, ...
    const int SW = gridDim.x * 4;
    const int W  = blockIdx.x * 4 + wid;
    int cnt = (W < nt) ? ((nt - 1 - W) / SW + 1) : 0;

    f32x4 cfA, cfB;
    i32x4 lbA, lbB;

    if (cnt > 0) {
        STAGE(0, W, cfA, lbA);
        int i = 0;
        while (true) {
            // phase A: compute buf0 (tile W+i*SW), prefetch buf1 (next tile)
            if (i + 1 < cnt) { STAGE(1, W + (size_t)(i + 1) * SW, cfB, lbB); WAIT8(); }
            else             { WAIT0(); }
            __builtin_amdgcn_sched_barrier(0);
            COMPUTE(0, cfA, lbA);
            if (++i >= cnt) break;
            // phase B: compute buf1, prefetch buf0
            if (i + 1 < cnt) { STAGE(0, W + (size_t)(i + 1) * SW, cfA, lbA); WAIT8(); }
            else             { WAIT0(); }
            __builtin_amdgcn_sched_barrier(0);
            COMPUTE(1, cfB, lbB);
            if (++i >= cnt) break;
        }
    }

    // remainder samples (B % TPS != 0; not taken for B = 8388608)
    long long done = (long long)nt * TPS;
    if (done < B) {
        const float* lf = (const float*)l4;
        const float* sf = (const float*)s4;
        for (long long s = done + (long long)(blockIdx.x * 4 + wid) * 64 + lane; s < B;
             s += (long long)SW * 64)
            part += sample_contrib(lf[3 * s], lf[3 * s + 1], lf[3 * s + 2],
                                   sf[3 * s], sf[3 * s + 1], sf[3 * s + 2],
                                   conf[s], hard[s]);
    }

#undef STAGE
#undef WAIT8
#undef WAIT0
#undef COMPUTE

    // wave-level reduction, one atomic per wave; no __syncthreads in the kernel
    double acc = (double)part;
#pragma unroll
    for (int off = 32; off > 0; off >>= 1)
        acc += __shfl_down(acc, off, 64);
    if (lane == 0)
        atomicAdd(ws_sum, acc);
}

__global__ void adl_finalize(const double* __restrict__ ws,
                             float* __restrict__ out, double invB) {
    out[0] = (float)(ws[0] * invB);
}

extern "C" void kernel_launch(void* const* d_in, const int* in_sizes, int n_in,
                              void* d_out, int out_size, void* d_ws, size_t ws_size,
                              hipStream_t stream) {
    const float* logits = (const float*)d_in[0];
    const int*   hard   = (const int*)d_in[1];
    const float* soft   = (const float*)d_in[2];
    const float* conf   = (const float*)d_in[3];

    long long B = in_sizes[1];      // batch size
    int nt = (int)(B / TPS);        // 32768 wave-tiles for B = 8388608

    double* ws = (double*)d_ws;
    hipMemsetAsync(ws, 0, sizeof(double), stream);

    int grid = GRID0;
    int need = (nt + 3) / 4;        // blocks so every stream has >=1 tile
    if (need < 1) need = 1;
    if (need < grid) grid = need;   // nt=32768 -> grid=2048, 4 tiles per stream

    adl_main<<<grid, BLOCK, 0, stream>>>((const float4*)logits, hard,
                                         (const float4*)soft, conf,
                                         ws, nt, B);
    adl_finalize<<<1, 1, 0, stream>>>(ws, (float*)d_out, 1.0 / (double)B);
}

// Round 7
// 246.117 us; speedup vs baseline: 1.2525x; 1.2525x over previous
//
#include <hip/hip_runtime.h>

static constexpr int BLOCK = 256;
static constexpr int SPT   = 4;              // CONSECUTIVE samples per thread per tile
static constexpr int SPB   = BLOCK * SPT;    // 1024 samples per tile
static constexpr int F4PT  = SPB * 3 / 4;    // 768 float4 per array per tile
static constexpr int GRID0 = 2048;           // 8192 tiles / 2048 = 4 tiles/block exactly

typedef float f32x4 __attribute__((ext_vector_type(4)));
typedef int   i32x4 __attribute__((ext_vector_type(4)));

__device__ __forceinline__ float sample_contrib(float l0, float l1, float l2,
                                                float t0, float t1, float t2,
                                                float c, int lab) {
    float temp;
    if (c > 0.9f)      temp = 1.5f;
    else if (c > 0.6f) temp = 2.0f;
    else               temp = fminf(2.5f + (0.6f - c) * 2.0f, 3.0f);
    float invT = 1.0f / temp;

    float a0 = l0 * invT, a1 = l1 * invT, a2 = l2 * invT;
    float m  = fmaxf(a0, fmaxf(a1, a2));
    float s  = __expf(a0 - m) + __expf(a1 - m) + __expf(a2 - m);
    float lse = __logf(s) + m;

    float tlogt = t0 * __logf(t0) + t1 * __logf(t1) + t2 * __logf(t2);
    float ta    = t0 * a0 + t1 * a1 + t2 * a2;
    float kl    = tlogt - ta + lse;

    float m2 = fmaxf(l0, fmaxf(l1, l2));
    float s2 = __expf(l0 - m2) + __expf(l1 - m2) + __expf(l2 - m2);
    float lse2 = __logf(s2) + m2;
    float ll = (lab == 0) ? l0 : ((lab == 1) ? l1 : l2);
    float ce = lse2 - ll;

    return 0.5f * kl + 0.5f * ce;
}

// Round-4 winning skeleton (barriered block convoys, NT on big arrays, counted
// vmcnt double-buffer) with ONE change: per-tile, thread t owns 4 CONSECUTIVE
// samples (4t..4t+3), so conf/hard collapse from 8 scalar dword loads to one
// float4 + one int4 per thread (16 B/lane -- the coalescing sweet spot).
// Stage drops from 14 vmem ops (512 of 896 lane-requests were 4 B) to 8 vmem
// ops, all 16 B/lane. LDS compute reads become 3x ds_read_b128 at word-stride
// 12: 8 lanes tile all 32 banks exactly, 0 conflicts (verified in round 6).
__global__ __launch_bounds__(BLOCK) void adl_main(
    const float4* __restrict__ l4,
    const int*    __restrict__ hard,
    const float4* __restrict__ s4,
    const float*  __restrict__ conf,
    double*       __restrict__ ws_sum,
    int nt, long long B)
{
    __shared__ __align__(16) float ldsL[2][SPB * 3];   // 2 x 12288 B
    __shared__ __align__(16) float ldsS[2][SPB * 3];   // 2 x 12288 B (48 KiB)

    const int t   = threadIdx.x;
    const int bid = blockIdx.x;
    const int G   = gridDim.x;
    float part = 0.0f;

    // 8 vmem ops per STAGE: 6 global_load_lds (NT) + 1 conf float4 + 1 hard int4.
#define STAGE(BUF, TILE, CF, LB)                                                   \
    do {                                                                           \
        const float4* gl_ = l4 + (size_t)(TILE) * F4PT;                            \
        const float4* gs_ = s4 + (size_t)(TILE) * F4PT;                            \
        _Pragma("unroll")                                                          \
        for (int k = 0; k < 3; ++k)                                                \
            __builtin_amdgcn_global_load_lds(                                      \
                (const __attribute__((address_space(1))) void*)(gl_ + k * BLOCK + t), \
                (__attribute__((address_space(3))) void*)(&ldsL[BUF][(k * BLOCK + t) * 4]), \
                16, 0, 2 /* CPol NT */);                                           \
        _Pragma("unroll")                                                          \
        for (int k = 0; k < 3; ++k)                                                \
            __builtin_amdgcn_global_load_lds(                                      \
                (const __attribute__((address_space(1))) void*)(gs_ + k * BLOCK + t), \
                (__attribute__((address_space(3))) void*)(&ldsS[BUF][(k * BLOCK + t) * 4]), \
                16, 0, 2 /* CPol NT */);                                           \
        CF = ((const f32x4*)conf)[(size_t)(TILE) * BLOCK + t];                     \
        LB = ((const i32x4*)hard)[(size_t)(TILE) * BLOCK + t];                     \
    } while (0)

#define WAIT8() asm volatile("s_waitcnt vmcnt(8)" ::: "memory")
#define WAIT0() asm volatile("s_waitcnt vmcnt(0)" ::: "memory")
#define BAR()                                    \
    do {                                         \
        __builtin_amdgcn_s_barrier();            \
        __builtin_amdgcn_sched_barrier(0);       \
    } while (0)

    // thread t reads LDS words 12t..12t+11: 3x ds_read_b128, byte addr 48t+{0,16,32}.
    // Lanes 0..7 cover all 32 banks exactly once per b128; 0 conflicts (R6-verified).
#define COMPUTE(BUF, CF, LB)                                                       \
    do {                                                                           \
        const float* Lp = &ldsL[BUF][12 * t];                                      \
        const float* Sp = &ldsS[BUF][12 * t];                                      \
        f32x4 L0 = *(const f32x4*)(Lp);                                            \
        f32x4 L1 = *(const f32x4*)(Lp + 4);                                        \
        f32x4 L2 = *(const f32x4*)(Lp + 8);                                        \
        f32x4 S0 = *(const f32x4*)(Sp);                                            \
        f32x4 S1 = *(const f32x4*)(Sp + 4);                                        \
        f32x4 S2 = *(const f32x4*)(Sp + 8);                                        \
        part += sample_contrib(L0[0], L0[1], L0[2], S0[0], S0[1], S0[2], CF[0], LB[0]); \
        part += sample_contrib(L0[3], L1[0], L1[1], S0[3], S1[0], S1[1], CF[1], LB[1]); \
        part += sample_contrib(L1[2], L1[3], L2[0], S1[2], S1[3], S2[0], CF[2], LB[2]); \
        part += sample_contrib(L2[1], L2[2], L2[3], S2[1], S2[2], S2[3], CF[3], LB[3]); \
    } while (0)

    // tiles for this block: bid, bid+G, bid+2G, ...  (uniform within block)
    int nb = (bid < nt) ? ((nt - 1 - bid) / G + 1) : 0;

    f32x4 cfA, cfB;
    i32x4 lbA, lbB;

    if (nb > 0) {
        STAGE(0, bid, cfA, lbA);
        int i = 0;
        while (true) {
            // ---- phase A: compute buf0 (tile i), prefetch into buf1 (tile i+1)
            {
                bool hn = (i + 1 < nb);
                if (hn) { STAGE(1, bid + (i + 1) * G, cfB, lbB); WAIT8(); }
                else    { WAIT0(); }
                BAR();
                COMPUTE(0, cfA, lbA);
                BAR();
            }
            if (++i >= nb) break;
            // ---- phase B: compute buf1 (tile i), prefetch into buf0 (tile i+1)
            {
                bool hn = (i + 1 < nb);
                if (hn) { STAGE(0, bid + (i + 1) * G, cfA, lbA); WAIT8(); }
                else    { WAIT0(); }
                BAR();
                COMPUTE(1, cfB, lbB);
                BAR();
            }
            if (++i >= nb) break;
        }
    }

    // remainder samples (B not a multiple of SPB; not taken for B = 8388608)
    long long done = (long long)nt * SPB;
    if (done < B) {
        const float* lf = (const float*)l4;
        const float* sf = (const float*)s4;
        for (long long s = done + (long long)bid * BLOCK + t; s < B;
             s += (long long)G * BLOCK)
            part += sample_contrib(lf[3 * s], lf[3 * s + 1], lf[3 * s + 2],
                                   sf[3 * s], sf[3 * s + 1], sf[3 * s + 2],
                                   conf[s], hard[s]);
    }

#undef STAGE
#undef WAIT8
#undef WAIT0
#undef BAR
#undef COMPUTE

    // block reduction -> one double atomic
    double acc = (double)part;
#pragma unroll
    for (int off = 32; off > 0; off >>= 1)
        acc += __shfl_down(acc, off, 64);

    __shared__ double red[BLOCK / 64];
    int lane = t & 63;
    int wid  = t >> 6;
    if (lane == 0) red[wid] = acc;
    __syncthreads();
    if (t == 0) {
        double s = 0.0;
#pragma unroll
        for (int i = 0; i < BLOCK / 64; ++i) s += red[i];
        atomicAdd(ws_sum, s);
    }
}

__global__ void adl_finalize(const double* __restrict__ ws,
                             float* __restrict__ out, double invB) {
    out[0] = (float)(ws[0] * invB);
}

extern "C" void kernel_launch(void* const* d_in, const int* in_sizes, int n_in,
                              void* d_out, int out_size, void* d_ws, size_t ws_size,
                              hipStream_t stream) {
    const float* logits = (const float*)d_in[0];
    const int*   hard   = (const int*)d_in[1];
    const float* soft   = (const float*)d_in[2];
    const float* conf   = (const float*)d_in[3];

    long long B = in_sizes[1];      // batch size
    int nt = (int)(B / SPB);        // 8192 full tiles for B = 8388608

    double* ws = (double*)d_ws;
    hipMemsetAsync(ws, 0, sizeof(double), stream);

    int grid = GRID0;
    if (nt < grid) grid = (nt > 0) ? nt : 1;   // nt=8192 -> 2048 blocks, 4 tiles each

    adl_main<<<grid, BLOCK, 0, stream>>>((const float4*)logits, hard,
                                         (const float4*)soft, conf,
                                         ws, nt, B);
    adl_finalize<<<1, 1, 0, stream>>>(ws, (float*)d_out, 1.0 / (double)B);
}

// Round 8
// 244.446 us; speedup vs baseline: 1.2611x; 1.0068x over previous
//
#include <hip/hip_runtime.h>

static constexpr int BLOCK = 256;
static constexpr int SPT   = 4;              // CONSECUTIVE samples per thread per tile
static constexpr int SPB   = BLOCK * SPT;    // 1024 samples per tile
static constexpr int F4PT  = SPB * 3 / 4;    // 768 float4 per array per tile
static constexpr int GRID0 = 2048;           // 8192 tiles / 2048 = 4 tiles/block exactly

typedef float f32x4 __attribute__((ext_vector_type(4)));
typedef int   i32x4 __attribute__((ext_vector_type(4)));

__device__ __forceinline__ float sample_contrib(float l0, float l1, float l2,
                                                float t0, float t1, float t2,
                                                float c, int lab) {
    float temp;
    if (c > 0.9f)      temp = 1.5f;
    else if (c > 0.6f) temp = 2.0f;
    else               temp = fminf(2.5f + (0.6f - c) * 2.0f, 3.0f);
    float invT = 1.0f / temp;

    float a0 = l0 * invT, a1 = l1 * invT, a2 = l2 * invT;
    float m  = fmaxf(a0, fmaxf(a1, a2));
    float s  = __expf(a0 - m) + __expf(a1 - m) + __expf(a2 - m);
    float lse = __logf(s) + m;

    float tlogt = t0 * __logf(t0) + t1 * __logf(t1) + t2 * __logf(t2);
    float ta    = t0 * a0 + t1 * a1 + t2 * a2;
    float kl    = tlogt - ta + lse;

    float m2 = fmaxf(l0, fmaxf(l1, l2));
    float s2 = __expf(l0 - m2) + __expf(l1 - m2) + __expf(l2 - m2);
    float lse2 = __logf(s2) + m2;
    float ll = (lab == 0) ? l0 : ((lab == 1) ? l1 : l2);
    float ce = lse2 - ll;

    return 0.5f * kl + 0.5f * ce;
}

// Round-7 kernel with ONE change: double buffer -> TRIPLE buffer (prefetch
// depth 2). Depth-1 waits on loads issued one compute-phase (~400-700 cyc)
// ago vs ~900 cyc HBM latency -> a convoy-wide latency stall every phase
// (VALUBusy 42%). Depth-2 gives each stage two compute-phases to land:
// steady-state s_waitcnt vmcnt(16) (two 8-op stages in flight), tail 16->8->0.
// Post-compute barrier retained: phase i's stage writes buf (i+2)%3, which is
// the buffer phase i-1 read -- the barrier orders read-before-overwrite.
__global__ __launch_bounds__(BLOCK) void adl_main(
    const float4* __restrict__ l4,
    const int*    __restrict__ hard,
    const float4* __restrict__ s4,
    const float*  __restrict__ conf,
    double*       __restrict__ ws_sum,
    int nt, long long B)
{
    __shared__ __align__(16) float ldsL[3][SPB * 3];   // 3 x 12288 B
    __shared__ __align__(16) float ldsS[3][SPB * 3];   // 3 x 12288 B (72 KiB -> 2 blk/CU)

    const int t   = threadIdx.x;
    const int bid = blockIdx.x;
    const int G   = gridDim.x;
    float part = 0.0f;

    // 8 vmem ops per STAGE: 6 global_load_lds (NT) + 1 conf float4 + 1 hard int4.
#define STAGE(BUF, TILE, CF, LB)                                                   \
    do {                                                                           \
        const float4* gl_ = l4 + (size_t)(TILE) * F4PT;                            \
        const float4* gs_ = s4 + (size_t)(TILE) * F4PT;                            \
        _Pragma("unroll")                                                          \
        for (int k = 0; k < 3; ++k)                                                \
            __builtin_amdgcn_global_load_lds(                                      \
                (const __attribute__((address_space(1))) void*)(gl_ + k * BLOCK + t), \
                (__attribute__((address_space(3))) void*)(&ldsL[BUF][(k * BLOCK + t) * 4]), \
                16, 0, 2 /* CPol NT */);                                           \
        _Pragma("unroll")                                                          \
        for (int k = 0; k < 3; ++k)                                                \
            __builtin_amdgcn_global_load_lds(                                      \
                (const __attribute__((address_space(1))) void*)(gs_ + k * BLOCK + t), \
                (__attribute__((address_space(3))) void*)(&ldsS[BUF][(k * BLOCK + t) * 4]), \
                16, 0, 2 /* CPol NT */);                                           \
        CF = ((const f32x4*)conf)[(size_t)(TILE) * BLOCK + t];                     \
        LB = ((const i32x4*)hard)[(size_t)(TILE) * BLOCK + t];                     \
    } while (0)

#define WAIT16() asm volatile("s_waitcnt vmcnt(16)" ::: "memory")
#define WAIT8()  asm volatile("s_waitcnt vmcnt(8)"  ::: "memory")
#define WAIT0()  asm volatile("s_waitcnt vmcnt(0)"  ::: "memory")
#define BAR()                                    \
    do {                                         \
        __builtin_amdgcn_s_barrier();            \
        __builtin_amdgcn_sched_barrier(0);       \
    } while (0)

    // thread t reads LDS words 12t..12t+11: 3x ds_read_b128, byte addr 48t+{0,16,32}.
    // Lanes 0..7 cover all 32 banks exactly once per b128; 0 conflicts (verified R6/R7).
#define COMPUTE(BUF, CF, LB)                                                       \
    do {                                                                           \
        const float* Lp = &ldsL[BUF][12 * t];                                      \
        const float* Sp = &ldsS[BUF][12 * t];                                      \
        f32x4 L0 = *(const f32x4*)(Lp);                                            \
        f32x4 L1 = *(const f32x4*)(Lp + 4);                                        \
        f32x4 L2 = *(const f32x4*)(Lp + 8);                                        \
        f32x4 S0 = *(const f32x4*)(Sp);                                            \
        f32x4 S1 = *(const f32x4*)(Sp + 4);                                        \
        f32x4 S2 = *(const f32x4*)(Sp + 8);                                        \
        part += sample_contrib(L0[0], L0[1], L0[2], S0[0], S0[1], S0[2], CF[0], LB[0]); \
        part += sample_contrib(L0[3], L1[0], L1[1], S0[3], S1[0], S1[1], CF[1], LB[1]); \
        part += sample_contrib(L1[2], L1[3], L2[0], S1[2], S1[3], S2[0], CF[2], LB[2]); \
        part += sample_contrib(L2[1], L2[2], L2[3], S2[1], S2[2], S2[3], CF[3], LB[3]); \
    } while (0)

    // One pipeline phase: compute buf CB (tile i), prefetch tile i+2 into buf PB.
    // Wait ladder: 2 stages in flight -> 16; 1 -> 8; none -> 0.
#define PHASE(CB, CCF, CLB, PB, PCF, PLB)                                          \
    do {                                                                           \
        bool h2 = (i + 2 < nb);                                                    \
        bool h1 = (i + 1 < nb);                                                    \
        if (h2) STAGE(PB, bid + (size_t)(i + 2) * G, PCF, PLB);                    \
        if (h2)      WAIT16();                                                     \
        else if (h1) WAIT8();                                                      \
        else         WAIT0();                                                      \
        BAR();                                                                     \
        COMPUTE(CB, CCF, CLB);                                                     \
        BAR();                                                                     \
    } while (0)

    // tiles for this block: bid, bid+G, bid+2G, ...  (uniform within block)
    int nb = (bid < nt) ? ((nt - 1 - bid) / G + 1) : 0;

    f32x4 cfA, cfB, cfC;
    i32x4 lbA, lbB, lbC;

    if (nb > 0) {
        STAGE(0, bid, cfA, lbA);
        if (nb > 1) STAGE(1, bid + (size_t)G, cfB, lbB);
        int i = 0;
        while (true) {
            PHASE(0, cfA, lbA, 2, cfC, lbC);  if (++i >= nb) break;
            PHASE(1, cfB, lbB, 0, cfA, lbA);  if (++i >= nb) break;
            PHASE(2, cfC, lbC, 1, cfB, lbB);  if (++i >= nb) break;
        }
    }

    // remainder samples (B not a multiple of SPB; not taken for B = 8388608)
    long long done = (long long)nt * SPB;
    if (done < B) {
        const float* lf = (const float*)l4;
        const float* sf = (const float*)s4;
        for (long long s = done + (long long)bid * BLOCK + t; s < B;
             s += (long long)G * BLOCK)
            part += sample_contrib(lf[3 * s], lf[3 * s + 1], lf[3 * s + 2],
                                   sf[3 * s], sf[3 * s + 1], sf[3 * s + 2],
                                   conf[s], hard[s]);
    }

#undef STAGE
#undef WAIT16
#undef WAIT8
#undef WAIT0
#undef BAR
#undef COMPUTE
#undef PHASE

    // block reduction -> one double atomic
    double acc = (double)part;
#pragma unroll
    for (int off = 32; off > 0; off >>= 1)
        acc += __shfl_down(acc, off, 64);

    __shared__ double red[BLOCK / 64];
    int lane = t & 63;
    int wid  = t >> 6;
    if (lane == 0) red[wid] = acc;
    __syncthreads();
    if (t == 0) {
        double s = 0.0;
#pragma unroll
        for (int i = 0; i < BLOCK / 64; ++i) s += red[i];
        atomicAdd(ws_sum, s);
    }
}

__global__ void adl_finalize(const double* __restrict__ ws,
                             float* __restrict__ out, double invB) {
    out[0] = (float)(ws[0] * invB);
}

extern "C" void kernel_launch(void* const* d_in, const int* in_sizes, int n_in,
                              void* d_out, int out_size, void* d_ws, size_t ws_size,
                              hipStream_t stream) {
    const float* logits = (const float*)d_in[0];
    const int*   hard   = (const int*)d_in[1];
    const float* soft   = (const float*)d_in[2];
    const float* conf   = (const float*)d_in[3];

    long long B = in_sizes[1];      // batch size
    int nt = (int)(B / SPB);        // 8192 full tiles for B = 8388608

    double* ws = (double*)d_ws;
    hipMemsetAsync(ws, 0, sizeof(double), stream);

    int grid = GRID0;
    if (nt < grid) grid = (nt > 0) ? nt : 1;   // nt=8192 -> 2048 blocks, 4 tiles each

    adl_main<<<grid, BLOCK, 0, stream>>>((const float4*)logits, hard,
                                         (const float4*)soft, conf,
                                         ws, nt, B);
    adl_finalize<<<1, 1, 0, stream>>>(ws, (float*)d_out, 1.0 / (double)B);
}